// Round 10
// baseline (325.452 us; speedup 1.0000x reference)
//
#include <hip/hip_runtime.h>
#include <hip/hip_cooperative_groups.h>
#include <math.h>

namespace cg = cooperative_groups;

#define L 16384
#define H 128
#define P 256
#define CL 32
#define NCH (L/CL)   // 512 chunks
#define GS 16        // chunks per group
#define NG (NCH/GS)  // 32 groups
#define KDIM 512     // out-GEMM K = [x2re | x2im]
#define NBU 512      // bu-GEMM N  = [BuRe | BuIm]

typedef __attribute__((ext_vector_type(8))) short short8;   // 8 bf16
typedef __attribute__((ext_vector_type(4))) float f32x4;

__device__ inline unsigned short f2bf(float f){          // fp32 -> bf16 RNE
  union { float f; unsigned u; } v; v.f = f;
  unsigned u = v.u;
  u += 0x7fffu + ((u >> 16) & 1u);
  return (unsigned short)(u >> 16);
}
__device__ inline float bf2f(unsigned short s){
  union { unsigned u; float f; } v; v.u = ((unsigned)s) << 16;
  return v.f;
}

struct Params { float M11,M12,M21,M22,s1,s2; };

__device__ inline Params get_params(const float* A_diag, const float* steps, int p){
  float A = A_diag[p]; A = A > 0.f ? A : 0.f;          // relu
  float dt = 1.f/(1.f + expf(-steps[p]));              // sigmoid
  float schur = 1.f/(1.f + dt*dt*A);
  Params q;
  q.M11 = 1.f - dt*dt*A*schur;
  q.M12 = -dt*A*schur;
  q.M21 = dt*schur;
  q.M22 = schur;
  q.s1 = q.M11*dt;
  q.s2 = q.M21*dt;
  return q;
}

// ---- shared helper: MFMA one chunk of Bu into LDS (bf16), 8 waves ----------
__device__ inline void chunk_bu_to_lds(int c, const short* __restrict__ inb,
                                       const short* __restrict__ BWswz,
                                       unsigned short (*sBu)[NBU+8]){
  int tid = threadIdx.x;
  int lane = tid & 63, w = tid >> 6;
  int ml = lane & 15, quad = lane >> 4;
  int mt = w & 1, ng = w >> 1;
  int lm0 = mt*16;
  const short* aptr = inb + (size_t)(c*CL + lm0 + ml)*H + quad*8;
  short8 av[4];
  #pragma unroll
  for (int ks=0; ks<4; ks++) av[ks] = *(const short8*)(aptr + ks*32);
  f32x4 acc[8];
  #pragma unroll
  for (int t=0;t<8;t++) acc[t] = (f32x4){0.f,0.f,0.f,0.f};
  #pragma unroll
  for (int ks=0; ks<4; ks++){
    #pragma unroll
    for (int t=0;t<8;t++){
      int n0 = (ng*8 + t)*16;
      short8 bv = *(const short8*)(BWswz + ((size_t)(ks*4+quad)*NBU + n0 + ml)*8);
      acc[t] = __builtin_amdgcn_mfma_f32_16x16x32_bf16(av[ks], bv, acc[t], 0, 0, 0);
    }
  }
  #pragma unroll
  for (int t=0;t<8;t++){
    int n = (ng*8+t)*16 + ml;
    #pragma unroll
    for (int r=0;r<4;r++)
      sBu[lm0 + quad*4 + r][n] = f2bf(acc[t][r]);
  }
}

// ======================= MEGA (cooperative, one launch) ======================
__global__ __launch_bounds__(512, 4) void linoss_mega(
    const float* __restrict__ in, const float* __restrict__ A_diag,
    const float* __restrict__ B, const float* __restrict__ Cw,
    const float* __restrict__ Dv, const float* __restrict__ steps,
    unsigned short* __restrict__ inb, unsigned short* __restrict__ BWswz,
    unsigned short* __restrict__ Bswz, float* finals,
    float* __restrict__ gfin, float* __restrict__ Yarr,
    float* __restrict__ out){
  cg::grid_group grid = cg::this_grid();
  __shared__ unsigned short sX[CL][NBU+8];     // 33.3 KB, persists across phases
  int tid = threadIdx.x;
  int c = blockIdx.x;

  // ---- P0: prep (cast input; both weight swizzles) ----
  {
    int gid = c*512 + tid;                     // 0..262143 == L*H/8
    const float4* g = (const float4*)in;
    float4 a = g[gid*2], b4 = g[gid*2+1];
    union { short8 s; unsigned short u[8]; } o;
    o.u[0]=f2bf(a.x); o.u[1]=f2bf(a.y); o.u[2]=f2bf(a.z); o.u[3]=f2bf(a.w);
    o.u[4]=f2bf(b4.x); o.u[5]=f2bf(b4.y); o.u[6]=f2bf(b4.z); o.u[7]=f2bf(b4.w);
    ((short8*)inb)[gid] = o.s;
    if (gid < H*NBU){                          // BW swizzle (k=h 0..127, n 0..511)
      int k = gid >> 9, n = gid & 511;
      int p = n & 255, c2 = n >> 8;
      float v = B[((size_t)p*H + k)*2 + c2];
      BWswz[((size_t)(k>>3)*NBU + n)*8 + (k&7)] = f2bf(v);
    }
    if (gid < KDIM*H){                         // C swizzle (k 0..511, n=h 0..127)
      int k = gid >> 7, n = gid & 127;
      float v = (k < P) ? Cw[((size_t)n*P + k)*2]
                        : -Cw[((size_t)n*P + (k-P))*2 + 1];
      Bswz[((size_t)(k>>3)*H + n)*8 + (k&7)] = f2bf(v);
    }
  }
  grid.sync();

  // ---- P1: Bu chunk -> LDS (persists), local scan -> chunk finals ----
  chunk_bu_to_lds(c, (const short*)inb, (const short*)BWswz, sX);
  __syncthreads();
  {
    int p = tid & 255, part = tid >> 8;
    Params q = get_params(A_diag, steps, p);
    float x1=0.f, x2=0.f;
    #pragma unroll
    for (int i=0;i<CL;i++){
      float u = bf2f(sX[i][part*256 + p]);
      float n1 = q.M11*x1 + q.M12*x2 + q.s1*u;
      float n2 = q.M21*x1 + q.M22*x2 + q.s2*u;
      x1 = n1; x2 = n2;
    }
    ((float2*)finals)[(size_t)(part*NCH + c)*P + p] = make_float2(x1,x2);
  }
  grid.sync();

  // ---- P2: per-group scan of chunk finals (in place -> z), group final -> gfin ----
  if (c < NG){
    int p = tid & 255, part = tid >> 8;
    int g = c;
    Params q = get_params(A_diag, steps, p);
    float a=q.M11, b=q.M12, cc=q.M21, d=q.M22;
    #pragma unroll
    for (int s=0;s<5;s++){                     // T = M^32
      float na=a*a+b*cc, nb=a*b+b*d, nc=cc*a+d*cc, nd=cc*b+d*d;
      a=na;b=nb;cc=nc;d=nd;
    }
    float2* z2 = (float2*)finals;
    float x1=0.f, x2=0.f;
    #pragma unroll
    for (int i=0;i<GS;i++){
      size_t idx = (size_t)(part*NCH + g*GS + i)*P + p;
      float2 f = z2[idx];
      z2[idx] = make_float2(x1,x2);
      float n1 = a*x1 + b*x2 + f.x;
      float n2 = cc*x1 + d*x2 + f.y;
      x1=n1; x2=n2;
    }
    ((float2*)gfin)[(size_t)(part*NG + g)*P + p] = make_float2(x1,x2);
  }
  grid.sync();

  // ---- P3: serial combine of 32 group finals (block 0) ----
  if (c == 0){
    int p = tid & 255, part = tid >> 8;
    Params q = get_params(A_diag, steps, p);
    float a=q.M11, b=q.M12, cc=q.M21, d=q.M22;
    #pragma unroll
    for (int s=0;s<9;s++){                     // T_G = M^512
      float na=a*a+b*cc, nb=a*b+b*d, nc=cc*a+d*cc, nd=cc*b+d*d;
      a=na;b=nb;cc=nc;d=nd;
    }
    const float2* Z2 = (const float2*)gfin;
    float2* Y2 = (float2*)Yarr;
    float x1=0.f, x2=0.f;
    #pragma unroll
    for (int g=0; g<NG; g++){
      size_t idx = (size_t)(part*NG + g)*P + p;
      Y2[idx] = make_float2(x1,x2);
      float2 z = Z2[idx];
      float n1 = a*x1 + b*x2 + z.x;
      float n2 = cc*x1 + d*x2 + z.y;
      x1=n1; x2=n2;
    }
  }
  grid.sync();

  // ---- P4: scan w/ carry (in-place x2 over LDS Bu), then out-MFMA ----
  {
    int p = tid & 255, part = tid >> 8;
    int g = c >> 4, iw = c & (GS-1);
    Params q = get_params(A_diag, steps, p);
    float a=q.M11, b=q.M12, cc=q.M21, dd=q.M22;
    #pragma unroll
    for (int s=0;s<5;s++){                     // T = M^32
      float na=a*a+b*cc, nb=a*b+b*dd, nc=cc*a+dd*cc, nd=cc*b+dd*dd;
      a=na;b=nb;cc=nc;dd=nd;
    }
    float sa=1.f, sb=0.f, sc=0.f, sd=1.f;      // S = T^iw
    float wa=a, wb=b, wc=cc, wd=dd;
    #pragma unroll
    for (int bit=0; bit<4; bit++){
      if ((iw>>bit)&1){
        float na = wa*sa + wb*sc, nb = wa*sb + wb*sd;
        float nc = wc*sa + wd*sc, nd = wc*sb + wd*sd;
        sa=na; sb=nb; sc=nc; sd=nd;
      }
      float qa = wa*wa + wb*wc, qb = wa*wb + wb*wd;
      float qc = wc*wa + wd*wc, qd = wc*wb + wd*wd;
      wa=qa; wb=qb; wc=qc; wd=qd;
    }
    float2 Y = ((const float2*)Yarr)[(size_t)(part*NG + g)*P + p];
    float2 z = ((const float2*)finals)[(size_t)(part*NCH + c)*P + p];
    float x1 = sa*Y.x + sb*Y.y + z.x;
    float x2 = sc*Y.x + sd*Y.y + z.y;
    #pragma unroll
    for (int i=0;i<CL;i++){
      float u = bf2f(sX[i][part*256 + p]);
      float n1 = q.M11*x1 + q.M12*x2 + q.s1*u;
      float n2 = q.M21*x1 + q.M22*x2 + q.s2*u;
      x1 = n1; x2 = n2;
      sX[i][part*256 + p] = f2bf(x2);
    }
  }
  __syncthreads();
  {
    int lane = tid & 63, w = tid >> 6;
    int ml = lane & 15, quad = lane >> 4;
    int mt = w & 1;
    int ntb = (w >> 1) * 2;
    f32x4 acc[2];
    acc[0] = (f32x4){0.f,0.f,0.f,0.f};
    acc[1] = (f32x4){0.f,0.f,0.f,0.f};
    for (int ks=0; ks<KDIM/32; ks++){
      short8 av = *(const short8*)&sX[mt*16 + ml][ks*32 + quad*8];
      #pragma unroll
      for (int j=0;j<2;j++){
        short8 bv = *(const short8*)((const short*)Bswz +
                      ((size_t)(ks*4+quad)*H + (ntb+j)*16 + ml)*8);
        acc[j] = __builtin_amdgcn_mfma_f32_16x16x32_bf16(av, bv, acc[j], 0, 0, 0);
      }
    }
    #pragma unroll
    for (int j=0;j<2;j++){
      int h = (ntb+j)*16 + ml;
      float dv = Dv[h];
      #pragma unroll
      for (int r=0;r<4;r++){
        int l = c*CL + mt*16 + quad*4 + r;
        out[(size_t)l*H + h] = acc[j][r] + in[(size_t)l*H + h]*dv;
      }
    }
  }
}

// ======================= Fallback pipeline (7 launches) ======================
__global__ __launch_bounds__(256) void cast_in(const float* __restrict__ in,
                                               unsigned short* __restrict__ inb){
  int i = blockIdx.x * 256 + threadIdx.x;
  const float4* g = (const float4*)in;
  float4 a = g[i*2], b = g[i*2+1];
  union { short8 s; unsigned short u[8]; } o;
  o.u[0]=f2bf(a.x); o.u[1]=f2bf(a.y); o.u[2]=f2bf(a.z); o.u[3]=f2bf(a.w);
  o.u[4]=f2bf(b.x); o.u[5]=f2bf(b.y); o.u[6]=f2bf(b.z); o.u[7]=f2bf(b.w);
  ((short8*)inb)[i] = o.s;
}

__global__ __launch_bounds__(512) void bwswz_prep(const float* __restrict__ B,
                                                  unsigned short* __restrict__ BWswz){
  int k = blockIdx.x;
  int n = threadIdx.x;
  int p = n & 255, c = n >> 8;
  float v = B[((size_t)p*H + k)*2 + c];
  BWswz[((size_t)(k>>3)*NBU + n)*8 + (k&7)] = f2bf(v);
}

__global__ __launch_bounds__(128) void bswz_prep(const float* __restrict__ C,
                                                 unsigned short* __restrict__ Bswz){
  int k = blockIdx.x;
  int n = threadIdx.x;
  float v = (k < P) ? C[((size_t)n*P + k)*2]
                    : -C[((size_t)n*P + (k-P))*2 + 1];
  Bswz[((size_t)(k>>3)*H + n)*8 + (k&7)] = f2bf(v);
}

__global__ __launch_bounds__(512) void bu_finals(const short* __restrict__ inb,
                                                 const short* __restrict__ BWswz,
                                                 const float* __restrict__ A_diag,
                                                 const float* __restrict__ steps,
                                                 float* __restrict__ finals){
  __shared__ unsigned short sBu[CL][NBU+8];
  int c = blockIdx.x;
  chunk_bu_to_lds(c, inb, BWswz, sBu);
  __syncthreads();
  int tid = threadIdx.x;
  int p = tid & 255, part = tid >> 8;
  Params q = get_params(A_diag, steps, p);
  float x1=0.f, x2=0.f;
  #pragma unroll
  for (int i=0;i<CL;i++){
    float u = bf2f(sBu[i][part*256 + p]);
    float n1 = q.M11*x1 + q.M12*x2 + q.s1*u;
    float n2 = q.M21*x1 + q.M22*x2 + q.s2*u;
    x1 = n1; x2 = n2;
  }
  ((float2*)finals)[(size_t)(part*NCH + c)*P + p] = make_float2(x1,x2);
}

__global__ __launch_bounds__(512) void group_scan(const float* __restrict__ A_diag,
                                                  const float* __restrict__ steps,
                                                  float* zf,
                                                  float* __restrict__ gfin){
  int tid = threadIdx.x;
  int p = tid & (P-1);
  int part = tid >> 8;
  int g = blockIdx.x;
  Params q = get_params(A_diag, steps, p);
  float a=q.M11, b=q.M12, c=q.M21, d=q.M22;
  #pragma unroll
  for (int s=0;s<5;s++){
    float na=a*a+b*c, nb=a*b+b*d, nc=c*a+d*c, nd=c*b+d*d;
    a=na;b=nb;c=nc;d=nd;
  }
  float2* z2 = (float2*)zf;
  float x1=0.f, x2=0.f;
  #pragma unroll
  for (int i=0;i<GS;i++){
    size_t idx = (size_t)(part*NCH + g*GS + i)*P + p;
    float2 f = z2[idx];
    z2[idx] = make_float2(x1,x2);
    float n1 = a*x1 + b*x2 + f.x;
    float n2 = c*x1 + d*x2 + f.y;
    x1=n1; x2=n2;
  }
  ((float2*)gfin)[(size_t)(part*NG + g)*P + p] = make_float2(x1,x2);
}

__global__ __launch_bounds__(512) void group_combine(const float* __restrict__ A_diag,
                                                     const float* __restrict__ steps,
                                                     const float* __restrict__ gfin,
                                                     float* __restrict__ Yarr){
  int tid = threadIdx.x;
  int p = tid & (P-1);
  int part = tid >> 8;
  Params q = get_params(A_diag, steps, p);
  float a=q.M11, b=q.M12, c=q.M21, d=q.M22;
  #pragma unroll
  for (int s=0;s<9;s++){
    float na=a*a+b*c, nb=a*b+b*d, nc=c*a+d*c, nd=c*b+d*d;
    a=na;b=nb;c=nc;d=nd;
  }
  const float2* Z2 = (const float2*)gfin;
  float2* Y2 = (float2*)Yarr;
  float x1=0.f, x2=0.f;
  #pragma unroll
  for (int g=0; g<NG; g++){
    size_t idx = (size_t)(part*NG + g)*P + p;
    Y2[idx] = make_float2(x1,x2);
    float2 z = Z2[idx];
    float n1 = a*x1 + b*x2 + z.x;
    float n2 = c*x1 + d*x2 + z.y;
    x1=n1; x2=n2;
  }
}

__global__ __launch_bounds__(512) void fused_out(const short* __restrict__ inb,
                                                 const short* __restrict__ BWswz,
                                                 const short* __restrict__ Bswz,
                                                 const float* __restrict__ A_diag,
                                                 const float* __restrict__ steps,
                                                 const float* __restrict__ zloc,
                                                 const float* __restrict__ Yarr,
                                                 const float* __restrict__ Dv,
                                                 const float* __restrict__ in,
                                                 float* __restrict__ out){
  __shared__ unsigned short sX[CL][KDIM+8];
  int c = blockIdx.x;
  chunk_bu_to_lds(c, inb, BWswz, sX);
  __syncthreads();
  int tid = threadIdx.x;
  {
    int p = tid & 255, part = tid >> 8;
    int g = c >> 4, iw = c & (GS-1);
    Params q = get_params(A_diag, steps, p);
    float a=q.M11, b=q.M12, cc=q.M21, dd=q.M22;
    #pragma unroll
    for (int s=0;s<5;s++){
      float na=a*a+b*cc, nb=a*b+b*dd, nc=cc*a+dd*cc, nd=cc*b+dd*dd;
      a=na;b=nb;cc=nc;dd=nd;
    }
    float sa=1.f, sb=0.f, sc=0.f, sd=1.f;
    float wa=a, wb=b, wc=cc, wd=dd;
    #pragma unroll
    for (int bit=0; bit<4; bit++){
      if ((iw>>bit)&1){
        float na = wa*sa + wb*sc, nb = wa*sb + wb*sd;
        float nc = wc*sa + wd*sc, nd = wc*sb + wd*sd;
        sa=na; sb=nb; sc=nc; sd=nd;
      }
      float qa = wa*wa + wb*wc, qb = wa*wb + wb*wd;
      float qc = wc*wa + wd*wc, qd = wc*wb + wd*wd;
      wa=qa; wb=qb; wc=qc; wd=qd;
    }
    float2 Y = ((const float2*)Yarr)[(size_t)(part*NG + g)*P + p];
    float2 z = ((const float2*)zloc)[(size_t)(part*NCH + c)*P + p];
    float x1 = sa*Y.x + sb*Y.y + z.x;
    float x2 = sc*Y.x + sd*Y.y + z.y;
    #pragma unroll
    for (int i=0;i<CL;i++){
      float u = bf2f(sX[i][part*256 + p]);
      float n1 = q.M11*x1 + q.M12*x2 + q.s1*u;
      float n2 = q.M21*x1 + q.M22*x2 + q.s2*u;
      x1 = n1; x2 = n2;
      sX[i][part*256 + p] = f2bf(x2);
    }
  }
  __syncthreads();
  int lane = tid & 63, w = tid >> 6;
  int ml = lane & 15, quad = lane >> 4;
  int mt = w & 1;
  int ntb = (w >> 1) * 2;
  f32x4 acc[2];
  acc[0] = (f32x4){0.f,0.f,0.f,0.f};
  acc[1] = (f32x4){0.f,0.f,0.f,0.f};
  for (int ks=0; ks<KDIM/32; ks++){
    short8 av = *(const short8*)&sX[mt*16 + ml][ks*32 + quad*8];
    #pragma unroll
    for (int j=0;j<2;j++){
      short8 bv = *(const short8*)(Bswz + ((size_t)(ks*4+quad)*H + (ntb+j)*16 + ml)*8);
      acc[j] = __builtin_amdgcn_mfma_f32_16x16x32_bf16(av, bv, acc[j], 0, 0, 0);
    }
  }
  #pragma unroll
  for (int j=0;j<2;j++){
    int h = (ntb+j)*16 + ml;
    float dv = Dv[h];
    #pragma unroll
    for (int r=0;r<4;r++){
      int l = c*CL + mt*16 + quad*4 + r;
      out[(size_t)l*H + h] = acc[j][r] + in[(size_t)l*H + h]*dv;
    }
  }
}

extern "C" void kernel_launch(void* const* d_in, const int* in_sizes, int n_in,
                              void* d_out, int out_size, void* d_ws, size_t ws_size,
                              hipStream_t stream) {
  const float* in     = (const float*)d_in[0];   // (L,H)
  const float* A_diag = (const float*)d_in[1];   // (P,)
  const float* B      = (const float*)d_in[2];   // (P,H,2)
  const float* Cw     = (const float*)d_in[3];   // (H,P,2)
  const float* Dv     = (const float*)d_in[4];   // (H,)
  const float* steps  = (const float*)d_in[5];   // (P,)
  float* out = (float*)d_out;

  unsigned short* inb  = (unsigned short*)d_ws;              // L*H bf16 (4MB)
  unsigned short* BWswz= inb + (size_t)L*H;                  // 128*512 bf16 (128KB)
  unsigned short* Bswz = BWswz + (size_t)H*NBU;              // 512*128 bf16 (128KB)
  float* finals = (float*)(Bswz + (size_t)KDIM*H);           // 2*NCH*P*2 (2MB)
  float* gfin   = finals + (size_t)2*NCH*P*2;                // 2*NG*P*2 (128KB)
  float* Yarr   = gfin + (size_t)2*NG*P*2;                   // 2*NG*P*2 (128KB)

  void* args[] = {
    (void*)&in, (void*)&A_diag, (void*)&B, (void*)&Cw, (void*)&Dv, (void*)&steps,
    (void*)&inb, (void*)&BWswz, (void*)&Bswz,
    (void*)&finals, (void*)&gfin, (void*)&Yarr, (void*)&out
  };
  hipError_t err = hipLaunchCooperativeKernel((const void*)linoss_mega,
                                              dim3(NCH), dim3(512),
                                              args, 0, stream);
  if (err != hipSuccess) {
    // Fallback: proven 7-kernel pipeline (same math, same buffers)
    cast_in<<<(L*H)/(8*256), 256, 0, stream>>>(in, inb);
    bwswz_prep<<<H, 512, 0, stream>>>(B, BWswz);
    bswz_prep<<<KDIM, 128, 0, stream>>>(Cw, Bswz);
    bu_finals<<<NCH, 512, 0, stream>>>((const short*)inb, (const short*)BWswz,
                                       A_diag, steps, finals);
    group_scan<<<NG, 512, 0, stream>>>(A_diag, steps, finals, gfin);
    group_combine<<<1, 512, 0, stream>>>(A_diag, steps, gfin, Yarr);
    fused_out<<<NCH, 512, 0, stream>>>((const short*)inb, (const short*)BWswz,
                                       (const short*)Bswz, A_diag, steps,
                                       finals, Yarr, Dv, in, out);
  }
}

// Round 11
// 104.324 us; speedup vs baseline: 3.1196x; 3.1196x over previous
//
#include <hip/hip_runtime.h>
#include <math.h>

#define L 16384
#define H 128
#define P 256
#define CL 32
#define NCH (L/CL)   // 512 chunks
#define GS 16        // chunks per group
#define NG (NCH/GS)  // 32 groups
#define KDIM 512     // out-GEMM K = [x2re | x2im]
#define NBU 512      // bu-GEMM N  = [BuRe | BuIm]

typedef __attribute__((ext_vector_type(8))) short short8;   // 8 bf16
typedef __attribute__((ext_vector_type(4))) float f32x4;

__device__ inline unsigned short f2bf(float f){          // fp32 -> bf16 RNE
  union { float f; unsigned u; } v; v.f = f;
  unsigned u = v.u;
  u += 0x7fffu + ((u >> 16) & 1u);
  return (unsigned short)(u >> 16);
}
__device__ inline float bf2f(unsigned short s){
  union { unsigned u; float f; } v; v.u = ((unsigned)s) << 16;
  return v.f;
}

struct Params { float M11,M12,M21,M22,s1,s2; };

__device__ inline Params get_params(const float* A_diag, const float* steps, int p){
  float A = A_diag[p]; A = A > 0.f ? A : 0.f;          // relu
  float dt = 1.f/(1.f + expf(-steps[p]));              // sigmoid
  float schur = 1.f/(1.f + dt*dt*A);
  Params q;
  q.M11 = 1.f - dt*dt*A*schur;
  q.M12 = -dt*A*schur;
  q.M21 = dt*schur;
  q.M22 = schur;
  q.s1 = q.M11*dt;
  q.s2 = q.M21*dt;
  return q;
}

// ---- K0: fused prep — cast input to bf16 + both weight swizzles -------------
// grid 512 x 512 threads; gid covers L*H/8 = 262144 short8 elements.
__global__ __launch_bounds__(512) void prep_all(const float* __restrict__ in,
                                                const float* __restrict__ B,
                                                const float* __restrict__ Cw,
                                                unsigned short* __restrict__ inb,
                                                unsigned short* __restrict__ BWswz,
                                                unsigned short* __restrict__ Bswz){
  int gid = blockIdx.x*512 + threadIdx.x;
  const float4* g = (const float4*)in;
  float4 a = g[gid*2], b4 = g[gid*2+1];
  union { short8 s; unsigned short u[8]; } o;
  o.u[0]=f2bf(a.x); o.u[1]=f2bf(a.y); o.u[2]=f2bf(a.z); o.u[3]=f2bf(a.w);
  o.u[4]=f2bf(b4.x); o.u[5]=f2bf(b4.y); o.u[6]=f2bf(b4.z); o.u[7]=f2bf(b4.w);
  ((short8*)inb)[gid] = o.s;
  if (gid < H*NBU){                            // BW swizzle (k=h 0..127, n 0..511)
    int k = gid >> 9, n = gid & 511;
    int p = n & 255, c2 = n >> 8;
    float v = B[((size_t)p*H + k)*2 + c2];
    BWswz[((size_t)(k>>3)*NBU + n)*8 + (k&7)] = f2bf(v);
  }
  if (gid < KDIM*H){                           // C swizzle (k 0..511, n=h 0..127)
    int k = gid >> 7, n = gid & 127;
    float v = (k < P) ? Cw[((size_t)n*P + k)*2]
                      : -Cw[((size_t)n*P + (k-P))*2 + 1];
    Bswz[((size_t)(k>>3)*H + n)*8 + (k&7)] = f2bf(v);
  }
}

// ---- shared helper: MFMA one chunk of Bu into LDS (bf16), 8 waves ----------
__device__ inline void chunk_bu_to_lds(int c, const short* __restrict__ inb,
                                       const short* __restrict__ BWswz,
                                       unsigned short (*sBu)[NBU+8]){
  int tid = threadIdx.x;
  int lane = tid & 63, w = tid >> 6;
  int ml = lane & 15, quad = lane >> 4;
  int mt = w & 1, ng = w >> 1;
  int lm0 = mt*16;
  const short* aptr = inb + (size_t)(c*CL + lm0 + ml)*H + quad*8;
  short8 av[4];
  #pragma unroll
  for (int ks=0; ks<4; ks++) av[ks] = *(const short8*)(aptr + ks*32);
  f32x4 acc[8];
  #pragma unroll
  for (int t=0;t<8;t++) acc[t] = (f32x4){0.f,0.f,0.f,0.f};
  #pragma unroll
  for (int ks=0; ks<4; ks++){
    #pragma unroll
    for (int t=0;t<8;t++){
      int n0 = (ng*8 + t)*16;
      short8 bv = *(const short8*)(BWswz + ((size_t)(ks*4+quad)*NBU + n0 + ml)*8);
      acc[t] = __builtin_amdgcn_mfma_f32_16x16x32_bf16(av[ks], bv, acc[t], 0, 0, 0);
    }
  }
  #pragma unroll
  for (int t=0;t<8;t++){
    int n = (ng*8+t)*16 + ml;
    #pragma unroll
    for (int r=0;r<4;r++)
      sBu[lm0 + quad*4 + r][n] = f2bf(acc[t][r]);
  }
}

// ---- K1: per-chunk MFMA Bu -> LDS -> local scan -> chunk finals ------------
__global__ __launch_bounds__(512) void bu_finals(const short* __restrict__ inb,
                                                 const short* __restrict__ BWswz,
                                                 const float* __restrict__ A_diag,
                                                 const float* __restrict__ steps,
                                                 float* __restrict__ finals){
  __shared__ unsigned short sBu[CL][NBU+8];    // 33.3 KB
  int c = blockIdx.x;
  chunk_bu_to_lds(c, inb, BWswz, sBu);
  __syncthreads();
  int tid = threadIdx.x;
  int p = tid & 255, part = tid >> 8;
  Params q = get_params(A_diag, steps, p);
  float x1=0.f, x2=0.f;
  #pragma unroll
  for (int i=0;i<CL;i++){
    float u = bf2f(sBu[i][part*256 + p]);
    float n1 = q.M11*x1 + q.M12*x2 + q.s1*u;
    float n2 = q.M21*x1 + q.M22*x2 + q.s2*u;
    x1 = n1; x2 = n2;
  }
  ((float2*)finals)[(size_t)(part*NCH + c)*P + p] = make_float2(x1,x2);
}

// ---- K2: per-group local scan of chunk finals (in place -> z), group final -> gfin ----
__global__ __launch_bounds__(512) void group_scan(const float* __restrict__ A_diag,
                                                  const float* __restrict__ steps,
                                                  float* zf,
                                                  float* __restrict__ gfin){
  int tid = threadIdx.x;
  int p = tid & (P-1);
  int part = tid >> 8;
  int g = blockIdx.x;
  Params q = get_params(A_diag, steps, p);
  float a=q.M11, b=q.M12, c=q.M21, d=q.M22;
  #pragma unroll
  for (int s=0;s<5;s++){            // T = M^32
    float na=a*a+b*c, nb=a*b+b*d, nc=c*a+d*c, nd=c*b+d*d;
    a=na;b=nb;c=nc;d=nd;
  }
  float2* z2 = (float2*)zf;
  float x1=0.f, x2=0.f;
  #pragma unroll
  for (int i=0;i<GS;i++){
    size_t idx = (size_t)(part*NCH + g*GS + i)*P + p;
    float2 f = z2[idx];
    z2[idx] = make_float2(x1,x2);
    float n1 = a*x1 + b*x2 + f.x;
    float n2 = c*x1 + d*x2 + f.y;
    x1=n1; x2=n2;
  }
  ((float2*)gfin)[(size_t)(part*NG + g)*P + p] = make_float2(x1,x2);
}

// ---- K3: fused final — MFMA Bu -> LDS; on-the-fly Y_g; scan w/ carry
//          (in-place x2 over LDS); out = x2 @ Bswz + in*D via MFMA ------------
__global__ __launch_bounds__(512) void fused_out(const short* __restrict__ inb,
                                                 const short* __restrict__ BWswz,
                                                 const short* __restrict__ Bswz,
                                                 const float* __restrict__ A_diag,
                                                 const float* __restrict__ steps,
                                                 const float* __restrict__ zloc,
                                                 const float* __restrict__ gfin,
                                                 const float* __restrict__ Dv,
                                                 const float* __restrict__ in,
                                                 float* __restrict__ out){
  __shared__ unsigned short sX[CL][KDIM+8];    // Bu, overwritten in place by x2
  int c = blockIdx.x;
  chunk_bu_to_lds(c, inb, BWswz, sX);
  __syncthreads();

  int tid = threadIdx.x;
  {
    int p = tid & 255, part = tid >> 8;
    int g = c >> 4, iw = c & (GS-1);
    Params q = get_params(A_diag, steps, p);
    // T = M^32
    float a=q.M11, b=q.M12, cc=q.M21, dd=q.M22;
    #pragma unroll
    for (int s=0;s<5;s++){
      float na=a*a+b*cc, nb=a*b+b*dd, nc=cc*a+dd*cc, nd=cc*b+dd*dd;
      a=na;b=nb;cc=nc;dd=nd;
    }
    // S = T^iw (iw wave-uniform)
    float sa=1.f, sb=0.f, sc=0.f, sd=1.f;
    {
      float wa=a, wb=b, wc=cc, wd=dd;
      #pragma unroll
      for (int bit=0; bit<4; bit++){
        if ((iw>>bit)&1){
          float na = wa*sa + wb*sc, nb = wa*sb + wb*sd;
          float nc = wc*sa + wd*sc, nd = wc*sb + wd*sd;
          sa=na; sb=nb; sc=nc; sd=nd;
        }
        float qa = wa*wa + wb*wc, qb = wa*wb + wb*wd;
        float qc = wc*wa + wd*wc, qd = wc*wb + wd*wd;
        wa=qa; wb=qb; wc=qc; wd=qd;
      }
    }
    // T_G = M^512 = T^16 (4 more squarings)
    float ga=a, gb=b, gc=cc, gd=dd;
    #pragma unroll
    for (int s=0;s<4;s++){
      float na=ga*ga+gb*gc, nb=ga*gb+gb*gd, nc=gc*ga+gd*gc, nd=gc*gb+gd*gd;
      ga=na;gb=nb;gc=nc;gd=nd;
    }
    // Y_g = sequential combine over gfin[0..g-1] (g wave-uniform, <=31 iters, L2-hit)
    float y1=0.f, y2=0.f;
    const float2* Z2 = (const float2*)gfin;
    for (int j=0; j<g; j++){
      float2 z = Z2[(size_t)(part*NG + j)*P + p];
      float n1 = ga*y1 + gb*y2 + z.x;
      float n2 = gc*y1 + gd*y2 + z.y;
      y1=n1; y2=n2;
    }
    float2 zc = ((const float2*)zloc)[(size_t)(part*NCH + c)*P + p];
    float x1 = sa*y1 + sb*y2 + zc.x;
    float x2 = sc*y1 + sd*y2 + zc.y;
    #pragma unroll
    for (int i=0;i<CL;i++){
      float u = bf2f(sX[i][part*256 + p]);
      float n1 = q.M11*x1 + q.M12*x2 + q.s1*u;
      float n2 = q.M21*x1 + q.M22*x2 + q.s2*u;
      x1 = n1; x2 = n2;
      sX[i][part*256 + p] = f2bf(x2);
    }
  }
  __syncthreads();

  // out GEMM: 32 rows x 128 h, A from LDS, 2 n-tiles per wave
  int lane = tid & 63, w = tid >> 6;
  int ml = lane & 15, quad = lane >> 4;
  int mt = w & 1;
  int ntb = (w >> 1) * 2;
  f32x4 acc[2];
  acc[0] = (f32x4){0.f,0.f,0.f,0.f};
  acc[1] = (f32x4){0.f,0.f,0.f,0.f};
  for (int ks=0; ks<KDIM/32; ks++){
    short8 av = *(const short8*)&sX[mt*16 + ml][ks*32 + quad*8];
    #pragma unroll
    for (int j=0;j<2;j++){
      short8 bv = *(const short8*)(Bswz + ((size_t)(ks*4+quad)*H + (ntb+j)*16 + ml)*8);
      acc[j] = __builtin_amdgcn_mfma_f32_16x16x32_bf16(av, bv, acc[j], 0, 0, 0);
    }
  }
  #pragma unroll
  for (int j=0;j<2;j++){
    int h = (ntb+j)*16 + ml;
    float dv = Dv[h];
    #pragma unroll
    for (int r=0;r<4;r++){
      int l = c*CL + mt*16 + quad*4 + r;
      out[(size_t)l*H + h] = acc[j][r] + in[(size_t)l*H + h]*dv;
    }
  }
}

extern "C" void kernel_launch(void* const* d_in, const int* in_sizes, int n_in,
                              void* d_out, int out_size, void* d_ws, size_t ws_size,
                              hipStream_t stream) {
  const float* in     = (const float*)d_in[0];   // (L,H)
  const float* A_diag = (const float*)d_in[1];   // (P,)
  const float* B      = (const float*)d_in[2];   // (P,H,2)
  const float* Cw     = (const float*)d_in[3];   // (H,P,2)
  const float* Dv     = (const float*)d_in[4];   // (H,)
  const float* steps  = (const float*)d_in[5];   // (P,)
  float* out = (float*)d_out;

  unsigned short* inb  = (unsigned short*)d_ws;              // L*H bf16 (4MB)
  unsigned short* BWswz= inb + (size_t)L*H;                  // 128*512 bf16 (128KB)
  unsigned short* Bswz = BWswz + (size_t)H*NBU;              // 512*128 bf16 (128KB)
  float* finals = (float*)(Bswz + (size_t)KDIM*H);           // 2*NCH*P*2 (2MB) -> zloc
  float* gfin   = finals + (size_t)2*NCH*P*2;                // 2*NG*P*2 (128KB)

  prep_all<<<512, 512, 0, stream>>>(in, B, Cw, inb, BWswz, Bswz);
  bu_finals<<<NCH, 512, 0, stream>>>((const short*)inb, (const short*)BWswz,
                                     A_diag, steps, finals);
  group_scan<<<NG, 512, 0, stream>>>(A_diag, steps, finals, gfin);
  fused_out<<<NCH, 512, 0, stream>>>((const short*)inb, (const short*)BWswz,
                                     (const short*)Bswz, A_diag, steps,
                                     finals, gfin, Dv, in, out);
}